// Round 2
// baseline (6000.407 us; speedup 1.0000x reference)
//
#include <hip/hip_runtime.h>
#include <hip/hip_bf16.h>
#include <cstdint>
#include <cstddef>

#define BATCH 2
#define SEQ   4096
#define DIM   1024
#define NHEAD 16
#define HDIM  64
#define NBLK  64
#define NMID  62
#define NRAND 3
#define NLAYER 4
#define FFDIM 4096
#define ROWS  (BATCH*SEQ)   // 8192
#define KSPL  16            // key splits for global attention

using f32x4 = __attribute__((ext_vector_type(4))) float;
using s16x8 = __attribute__((ext_vector_type(8))) short;
using s16x4 = __attribute__((ext_vector_type(4))) short;

__device__ inline float bf2f(short s) {
    unsigned u = ((unsigned)(unsigned short)s) << 16;
    union { unsigned u; float f; } cv; cv.u = u; return cv.f;
}
__device__ inline short f2bf(float f) {
    union { float f; unsigned u; } cv; cv.f = f;
    unsigned u = cv.u;
    unsigned r = (u + 0x7fffu + ((u >> 16) & 1u)) >> 16;  // RNE
    return (short)r;
}
__device__ inline float gelu_f(float x) {
    float u = 0.7978845608028654f * (x + 0.044715f * x * x * x);
    return 0.5f * x * (1.f + tanhf(u));
}

// ---------------------------------------------------------------- embedding
__global__ __launch_bounds__(256) void embed_kernel(
    const int* __restrict__ ids, const float* __restrict__ emb, float* __restrict__ x)
{
    int row = blockIdx.x;
    int id  = ids[row];
    ((float4*)x)[(size_t)row * 256 + threadIdx.x] =
        ((const float4*)emb)[(size_t)id * 256 + threadIdx.x];
}

// ---------------------------------------------------------------- neg mask
__global__ __launch_bounds__(256) void neg_kernel(
    const int* __restrict__ mask, float* __restrict__ neg)
{
    int i = blockIdx.x * 256 + threadIdx.x;
    if (i < ROWS) neg[i] = (1.f - (float)mask[i]) * -1e9f;
}

// ---------------------------------------------------------------- layernorm (row=1024)
template<int OUTBF>
__global__ __launch_bounds__(256) void ln_kernel(
    const float* __restrict__ x, const float* __restrict__ g,
    const float* __restrict__ bia, void* __restrict__ out)
{
    __shared__ float s1[4], s2[4];
    int row = blockIdx.x, t = threadIdx.x;
    const float* xr = x + (size_t)row * DIM;
    float4 v = ((const float4*)xr)[t];
    float s = v.x + v.y + v.z + v.w;
    #pragma unroll
    for (int o = 32; o > 0; o >>= 1) s += __shfl_xor(s, o, 64);
    if ((t & 63) == 0) s1[t >> 6] = s;
    __syncthreads();
    float mu = (s1[0] + s1[1] + s1[2] + s1[3]) * (1.f / DIM);
    float dx = v.x - mu, dy = v.y - mu, dz = v.z - mu, dw = v.w - mu;
    float q = dx*dx + dy*dy + dz*dz + dw*dw;
    #pragma unroll
    for (int o = 32; o > 0; o >>= 1) q += __shfl_xor(q, o, 64);
    if ((t & 63) == 0) s2[t >> 6] = q;
    __syncthreads();
    float var = (s2[0] + s2[1] + s2[2] + s2[3]) * (1.f / DIM);
    float rs  = rsqrtf(var + 1e-5f);
    float4 gg = ((const float4*)g)[t];
    float4 bb = ((const float4*)bia)[t];
    float o0 = dx * rs * gg.x + bb.x;
    float o1 = dy * rs * gg.y + bb.y;
    float o2 = dz * rs * gg.z + bb.z;
    float o3 = dw * rs * gg.w + bb.w;
    if (OUTBF) {
        s16x4 ov = { f2bf(o0), f2bf(o1), f2bf(o2), f2bf(o3) };
        ((s16x4*)out)[(size_t)row * (DIM/4) + t] = ov;
    } else {
        float4 ov = { o0, o1, o2, o3 };
        ((float4*)out)[(size_t)row * (DIM/4) + t] = ov;
    }
}

// ---------------------------------------------------------------- weight transpose + bf16
__global__ __launch_bounds__(256) void wconv_kernel(
    const float* __restrict__ W, short* __restrict__ Wt, int K, int N)
{
    __shared__ float tile[32][33];
    int k0 = blockIdx.x * 32, n0 = blockIdx.y * 32;
    int t = threadIdx.x;
    int r = t >> 3, c = (t & 7) * 4;
    float4 v = *(const float4*)(W + (size_t)(k0 + r) * N + n0 + c);
    tile[r][c+0] = v.x; tile[r][c+1] = v.y; tile[r][c+2] = v.z; tile[r][c+3] = v.w;
    __syncthreads();
    s16x4 ov;
    #pragma unroll
    for (int jj = 0; jj < 4; ++jj) ov[jj] = f2bf(tile[c + jj][r]);
    *(s16x4*)(Wt + (size_t)(n0 + r) * K + k0 + c) = ov;
}

// ---------------------------------------------------------------- GEMM (bf16 MFMA)
template<int EPI>
__global__ __launch_bounds__(256) void gemm_kernel(
    const short* __restrict__ A, const short* __restrict__ Bt,
    const float* __restrict__ bias, const float* __restrict__ resid,
    void* __restrict__ Cout, int M, int N, int K)
{
    __shared__ short As[128 * 64];
    __shared__ short Bs[128 * 64];
    const int t = threadIdx.x;
    const int m0 = blockIdx.x * 128, n0 = blockIdx.y * 128;
    const int lane = t & 63, wave = t >> 6;
    const int wr = (wave >> 1) * 64, wc = (wave & 1) * 64;
    const int srow = t >> 3;
    const int scolb = (t & 7) * 16;

    f32x4 acc[4][4];
    #pragma unroll
    for (int m = 0; m < 4; ++m)
        #pragma unroll
        for (int n = 0; n < 4; ++n)
            acc[m][n] = f32x4{0.f, 0.f, 0.f, 0.f};

    const short* Arow = A  + (size_t)(m0 + srow) * K + (scolb >> 1);
    const short* Brow = Bt + (size_t)(n0 + srow) * K + (scolb >> 1);

    for (int kt = 0; kt < K; kt += 64) {
        s16x8 ra[4], rb[4];
        #pragma unroll
        for (int p = 0; p < 4; ++p) {
            ra[p] = *(const s16x8*)(Arow + (size_t)(p * 32) * K + kt);
            rb[p] = *(const s16x8*)(Brow + (size_t)(p * 32) * K + kt);
        }
        __syncthreads();
        #pragma unroll
        for (int p = 0; p < 4; ++p) {
            int row = p * 32 + srow;
            int boff = row * 128 + (scolb ^ ((row & 7) << 4));
            *(s16x8*)((char*)As + boff) = ra[p];
            *(s16x8*)((char*)Bs + boff) = rb[p];
        }
        __syncthreads();
        #pragma unroll
        for (int kk = 0; kk < 2; ++kk) {
            s16x8 af[4], bfr[4];
            #pragma unroll
            for (int i = 0; i < 4; ++i) {
                int cb = kk * 64 + ((lane >> 4) << 4);
                int r  = wr + i * 16 + (lane & 15);
                af[i]  = *(const s16x8*)((const char*)As + r * 128 + (cb ^ ((r & 7) << 4)));
                int r2 = wc + i * 16 + (lane & 15);
                bfr[i] = *(const s16x8*)((const char*)Bs + r2 * 128 + (cb ^ ((r2 & 7) << 4)));
            }
            #pragma unroll
            for (int m = 0; m < 4; ++m)
                #pragma unroll
                for (int n = 0; n < 4; ++n)
                    acc[m][n] = __builtin_amdgcn_mfma_f32_16x16x32_bf16(
                        af[m], bfr[n], acc[m][n], 0, 0, 0);
        }
    }

    const int rbase = m0 + wr + ((lane >> 4) << 2);
    const int cbase = n0 + wc + (lane & 15);
    #pragma unroll
    for (int m = 0; m < 4; ++m) {
        #pragma unroll
        for (int n = 0; n < 4; ++n) {
            #pragma unroll
            for (int j = 0; j < 4; ++j) {
                int row = rbase + m * 16 + j;
                int col = cbase + n * 16;
                float val = acc[m][n][j] + bias[col];
                size_t idx = (size_t)row * N + col;
                if (EPI == 1) val = gelu_f(val);
                if (EPI == 2) ((float*)Cout)[idx] = val + resid[idx];
                else          ((short*)Cout)[idx] = f2bf(val);
            }
        }
    }
}

// ---------------------------------------------------------------- shared attention core
// 32 q-rows (already staged in Qs, scaled), iterate NKB key-blocks listed in kbl.
// Thread t owns row r=t>>3, key-group kg=t&7. Leaves running (mr, lsum, ca[8]).
template<int NKB>
__device__ inline void attn_core(
    const short* __restrict__ kmat, const short* __restrict__ vmat,
    const float* __restrict__ neg, int b, int h, const int* kbl,
    float (*Qs)[65], float (*KVs)[65], float (*Ps)[65],
    float (*redm)[9], float (*reds)[9], float* kmask,
    float& mr, float& lsum, float* ca)
{
    const int t = threadIdx.x;
    const int r = t >> 3, kg = t & 7;
    mr = -1e30f; lsum = 0.f;
    #pragma unroll
    for (int dd = 0; dd < 8; ++dd) ca[dd] = 0.f;

    #pragma unroll 1
    for (int ib = 0; ib < NKB; ++ib) {
        int kbn = kbl[ib];
        {   // stage K (64x64)
            int row = t >> 2, cc = (t & 3) * 16;
            const short* src = kmat + ((size_t)(b * SEQ + kbn * 64 + row)) * DIM + h * HDIM + cc;
            s16x8 a = ((const s16x8*)src)[0];
            s16x8 bb = ((const s16x8*)src)[1];
            #pragma unroll
            for (int i = 0; i < 8; ++i) {
                KVs[row][cc + i]     = bf2f(a[i]);
                KVs[row][cc + 8 + i] = bf2f(bb[i]);
            }
            if (t < 64) kmask[t] = neg[b * SEQ + kbn * 64 + t];
        }
        __syncthreads();
        float sv[8];
        #pragma unroll
        for (int kk = 0; kk < 8; ++kk) sv[kk] = 0.f;
        for (int d = 0; d < 64; ++d) {
            float qv = Qs[r][d];
            #pragma unroll
            for (int kk = 0; kk < 8; ++kk)
                sv[kk] = fmaf(qv, KVs[kg * 8 + kk][d], sv[kk]);
        }
        float lm = -1e30f;
        #pragma unroll
        for (int kk = 0; kk < 8; ++kk) {
            sv[kk] += kmask[kg * 8 + kk];
            lm = fmaxf(lm, sv[kk]);
        }
        redm[r][kg] = lm;
        __syncthreads();   // QK reads of KVs done -> safe to overwrite with V
        float mn = mr;
        #pragma unroll
        for (int i = 0; i < 8; ++i) mn = fmaxf(mn, redm[r][i]);
        float ls = 0.f;
        #pragma unroll
        for (int kk = 0; kk < 8; ++kk) {
            float p = __expf(sv[kk] - mn);
            Ps[r][kg * 8 + kk] = p;
            ls += p;
        }
        reds[r][kg] = ls;
        {   // stage V
            int row = t >> 2, cc = (t & 3) * 16;
            const short* src = vmat + ((size_t)(b * SEQ + kbn * 64 + row)) * DIM + h * HDIM + cc;
            s16x8 a = ((const s16x8*)src)[0];
            s16x8 bb = ((const s16x8*)src)[1];
            #pragma unroll
            for (int i = 0; i < 8; ++i) {
                KVs[row][cc + i]     = bf2f(a[i]);
                KVs[row][cc + 8 + i] = bf2f(bb[i]);
            }
        }
        __syncthreads();   // V, Ps, reds ready
        float f = __expf(mr - mn);
        mr = mn;
        float ps = 0.f;
        #pragma unroll
        for (int i = 0; i < 8; ++i) ps += reds[r][i];
        lsum = lsum * f + ps;
        #pragma unroll
        for (int dd = 0; dd < 8; ++dd) ca[dd] *= f;
        for (int ki = 0; ki < 64; ++ki) {
            float p = Ps[r][ki];
            #pragma unroll
            for (int dd = 0; dd < 8; ++dd)
                ca[dd] = fmaf(p, KVs[ki][kg * 8 + dd], ca[dd]);
        }
        __syncthreads();   // PV done before next K staging
    }
}

__device__ inline void stage_q32(const short* __restrict__ q, int b, int h, int q0,
                                 float (*Qs)[65])
{
    int t = threadIdx.x;
    int row = t >> 3, cc = (t & 7) * 8;
    const short* src = q + ((size_t)(b * SEQ + q0 + row)) * DIM + h * HDIM + cc;
    s16x8 a = *(const s16x8*)src;
    #pragma unroll
    for (int i = 0; i < 8; ++i) Qs[row][cc + i] = bf2f(a[i]) * 0.125f;
}

// ---------------------------------------------------------------- middle-block attention
// grid (NMID*2, H, B): q-block n=j+1 (32-row half), keys {n-1,n,n+1,0,63,r0,r1,r2}
__global__ __launch_bounds__(256) void attn_middle(
    const short* __restrict__ q, const short* __restrict__ k, const short* __restrict__ v,
    const float* __restrict__ neg, const int* __restrict__ rand_attn, short* __restrict__ ctx)
{
    __shared__ float Qs[32][65];
    __shared__ float KVs[64][65];
    __shared__ float Ps[32][65];
    __shared__ float redm[32][9];
    __shared__ float reds[32][9];
    __shared__ float kmask[64];

    const int jh = blockIdx.x, h = blockIdx.y, b = blockIdx.z;
    const int j = jh >> 1, half = jh & 1;
    const int n = j + 1;
    const int q0 = n * 64 + half * 32;
    const int t = threadIdx.x;

    stage_q32(q, b, h, q0, Qs);

    int kbl[8];
    kbl[0] = n - 1; kbl[1] = n; kbl[2] = n + 1; kbl[3] = 0; kbl[4] = NBLK - 1;
    {
        const int* ra = rand_attn + ((size_t)h * NMID + j) * NRAND;
        kbl[5] = ra[0]; kbl[6] = ra[1]; kbl[7] = ra[2];
    }
    float mr, lsum, ca[8];
    attn_core<8>(k, v, neg, b, h, kbl, Qs, KVs, Ps, redm, reds, kmask, mr, lsum, ca);

    const int r = t >> 3, kg = t & 7;
    float inv = 1.f / lsum;
    s16x8 o;
    #pragma unroll
    for (int dd = 0; dd < 8; ++dd) o[dd] = f2bf(ca[dd] * inv);
    *(s16x8*)(ctx + ((size_t)(b * SEQ + q0 + r)) * DIM + h * HDIM + kg * 8) = o;
}

// ---------------------------------------------------------------- global attention, split-K partials
// grid (4*KSPL, H, B): qchunk = bx>>4 (32 rows of blocks 0/63), ksplit = bx&15 (4 key-blocks)
// partial layout per (b,h,qc,ks): acc[32][64], m[32], l[32]  (2112 floats)
__global__ __launch_bounds__(256) void attn_global_part(
    const short* __restrict__ q, const short* __restrict__ k, const short* __restrict__ v,
    const float* __restrict__ neg, float* __restrict__ part)
{
    __shared__ float Qs[32][65];
    __shared__ float KVs[64][65];
    __shared__ float Ps[32][65];
    __shared__ float redm[32][9];
    __shared__ float reds[32][9];
    __shared__ float kmask[64];

    const int qc = blockIdx.x >> 4, ks = blockIdx.x & 15;
    const int h = blockIdx.y, b = blockIdx.z;
    const int q0 = (qc < 2) ? qc * 32 : (SEQ - 128 + (qc - 2) * 32 + 64);
    const int t = threadIdx.x;

    stage_q32(q, b, h, q0, Qs);

    int kbl[4];
    #pragma unroll
    for (int i = 0; i < 4; ++i) kbl[i] = ks * 4 + i;

    float mr, lsum, ca[8];
    attn_core<4>(k, v, neg, b, h, kbl, Qs, KVs, Ps, redm, reds, kmask, mr, lsum, ca);

    const int r = t >> 3, kg = t & 7;
    float* base = part + ((size_t)(((b * NHEAD + h) * 4 + qc) * KSPL + ks)) * 2112;
    #pragma unroll
    for (int dd = 0; dd < 8; ++dd) base[r * 64 + kg * 8 + dd] = ca[dd];
    if (kg == 0) { base[2048 + r] = mr; base[2080 + r] = lsum; }
}

// ---------------------------------------------------------------- merge global-attn partials
// grid (4, H, B); thread owns (r=t>>3, kg=t&7)
__global__ __launch_bounds__(256) void attn_greduce(
    const float* __restrict__ part, short* __restrict__ ctx)
{
    const int qc = blockIdx.x, h = blockIdx.y, b = blockIdx.z;
    const int q0 = (qc < 2) ? qc * 32 : (SEQ - 128 + (qc - 2) * 32 + 64);
    const int t = threadIdx.x;
    const int r = t >> 3, kg = t & 7;
    const float* base0 = part + ((size_t)(((b * NHEAD + h) * 4 + qc) * KSPL)) * 2112;

    float m = -1e30f;
    #pragma unroll 1
    for (int ks = 0; ks < KSPL; ++ks)
        m = fmaxf(m, base0[(size_t)ks * 2112 + 2048 + r]);
    float L = 0.f, acc[8] = {0,0,0,0,0,0,0,0};
    #pragma unroll 1
    for (int ks = 0; ks < KSPL; ++ks) {
        const float* bp = base0 + (size_t)ks * 2112;
        float w = __expf(bp[2048 + r] - m);
        L += w * bp[2080 + r];
        #pragma unroll
        for (int dd = 0; dd < 8; ++dd)
            acc[dd] = fmaf(w, bp[r * 64 + kg * 8 + dd], acc[dd]);
    }
    float inv = 1.f / L;
    s16x8 o;
    #pragma unroll
    for (int dd = 0; dd < 8; ++dd) o[dd] = f2bf(acc[dd] * inv);
    *(s16x8*)(ctx + ((size_t)(b * SEQ + q0 + r)) * DIM + h * HDIM + kg * 8) = o;
}

// ---------------------------------------------------------------- mean over S per (b,d)
__global__ __launch_bounds__(256) void colmean_kernel(
    const float* __restrict__ xln, float* __restrict__ feats)
{
    __shared__ float red[8][33];
    int c = blockIdx.x, b = blockIdx.y;
    int dd = threadIdx.x & 31, rg = threadIdx.x >> 5;
    const float* base = xln + (size_t)b * SEQ * DIM + c * 32 + dd;
    float s = 0.f;
    for (int rr = rg; rr < SEQ; rr += 8) s += base[(size_t)rr * DIM];
    red[rg][dd] = s;
    __syncthreads();
    if (rg == 0) {
        float tot = s;
        #pragma unroll
        for (int i = 1; i < 8; ++i) tot += red[i][dd];
        feats[b * DIM + c * 32 + dd] = tot * (1.f / SEQ);
    }
}

// ---------------------------------------------------------------- normalize + project
__global__ __launch_bounds__(256) void head_kernel(
    const float* __restrict__ feats, const float* __restrict__ projW,
    const float* __restrict__ projb, float* __restrict__ out)
{
    __shared__ float f[DIM];
    __shared__ float slots[4];
    int b = blockIdx.x, t = threadIdx.x;
    float ss = 0.f;
    for (int i = t; i < DIM; i += 256) {
        float vv = feats[b * DIM + i];
        f[i] = vv;
        ss += vv * vv;
    }
    #pragma unroll
    for (int o = 32; o > 0; o >>= 1) ss += __shfl_xor(ss, o, 64);
    if ((t & 63) == 0) slots[t >> 6] = ss;
    __syncthreads();
    float nrm = sqrtf(slots[0] + slots[1] + slots[2] + slots[3]);
    float inv = 1.f / fmaxf(nrm, 1e-12f);
    for (int o = t; o < 512; o += 256) {
        float acc = 0.f;
        for (int d = 0; d < DIM; ++d)
            acc = fmaf(f[d], projW[(size_t)d * 512 + o], acc);
        out[b * 512 + o] = acc * inv + projb[o];
    }
}

// ---------------------------------------------------------------- launch
extern "C" void kernel_launch(void* const* d_in, const int* in_sizes, int n_in,
                              void* d_out, int out_size, void* d_ws, size_t ws_size,
                              hipStream_t stream)
{
    (void)in_sizes; (void)n_in; (void)out_size; (void)ws_size;
    const int*   ids   = (const int*)d_in[0];
    const int*   amask = (const int*)d_in[1];
    const int*   rnd   = (const int*)d_in[2];
    const float* emb   = (const float*)d_in[3];
    const float* Wq    = (const float*)d_in[4];
    const float* bq    = (const float*)d_in[5];
    const float* Wk    = (const float*)d_in[6];
    const float* bk    = (const float*)d_in[7];
    const float* Wv    = (const float*)d_in[8];
    const float* bv    = (const float*)d_in[9];
    const float* Wo    = (const float*)d_in[10];
    const float* bo    = (const float*)d_in[11];
    const float* ln1g  = (const float*)d_in[12];
    const float* ln1b  = (const float*)d_in[13];
    const float* W1    = (const float*)d_in[14];
    const float* b1    = (const float*)d_in[15];
    const float* W2    = (const float*)d_in[16];
    const float* b2    = (const float*)d_in[17];
    const float* ln2g  = (const float*)d_in[18];
    const float* ln2b  = (const float*)d_in[19];
    const float* lnfg  = (const float*)d_in[20];
    const float* lnfb  = (const float*)d_in[21];
    const float* projW = (const float*)d_in[22];
    const float* projb = (const float*)d_in[23];
    float* out = (float*)d_out;

    char* ws = (char*)d_ws;
    size_t off = 0;
    float* x    = (float*)(ws + off); off += (size_t)ROWS * DIM * 4;
    float* xn_f = (float*)(ws + off);
    short* xn_b = (short*)(ws + off); off += (size_t)ROWS * DIM * 4;
    short* qb   = (short*)(ws + off); off += (size_t)ROWS * DIM * 2;
    short* kbuf = (short*)(ws + off); off += (size_t)ROWS * DIM * 2;
    short* vbuf = (short*)(ws + off); off += (size_t)ROWS * DIM * 2;
    short* ctxb = (short*)(ws + off); off += (size_t)ROWS * DIM * 2;
    short* ffb  = (short*)(ws + off); off += (size_t)ROWS * FFDIM * 2;
    short* wt   = (short*)(ws + off); off += (size_t)FFDIM * DIM * 2;
    float* neg  = (float*)(ws + off); off += (size_t)ROWS * 4;
    float* feats= (float*)(ws + off); off += (size_t)BATCH * DIM * 4;
    float* part = (float*)(ws + off); off += (size_t)BATCH * NHEAD * 4 * KSPL * 2112 * 4;

    embed_kernel<<<ROWS, 256, 0, stream>>>(ids, emb, x);
    neg_kernel<<<(ROWS + 255) / 256, 256, 0, stream>>>(amask, neg);

    for (int l = 0; l < NLAYER; ++l) {
        ln_kernel<1><<<ROWS, 256, 0, stream>>>(x, ln1g + l * DIM, ln1b + l * DIM, xn_b);

        wconv_kernel<<<dim3(DIM/32, DIM/32), 256, 0, stream>>>(Wq + (size_t)l*DIM*DIM, wt, DIM, DIM);
        gemm_kernel<0><<<dim3(ROWS/128, DIM/128), 256, 0, stream>>>(xn_b, wt, bq + l*DIM, nullptr, qb,   ROWS, DIM, DIM);
        wconv_kernel<<<dim3(DIM/32, DIM/32), 256, 0, stream>>>(Wk + (size_t)l*DIM*DIM, wt, DIM, DIM);
        gemm_kernel<0><<<dim3(ROWS/128, DIM/128), 256, 0, stream>>>(xn_b, wt, bk + l*DIM, nullptr, kbuf, ROWS, DIM, DIM);
        wconv_kernel<<<dim3(DIM/32, DIM/32), 256, 0, stream>>>(Wv + (size_t)l*DIM*DIM, wt, DIM, DIM);
        gemm_kernel<0><<<dim3(ROWS/128, DIM/128), 256, 0, stream>>>(xn_b, wt, bv + l*DIM, nullptr, vbuf, ROWS, DIM, DIM);

        attn_global_part<<<dim3(4 * KSPL, NHEAD, BATCH), 256, 0, stream>>>(qb, kbuf, vbuf, neg, part);
        attn_middle<<<dim3(NMID * 2, NHEAD, BATCH), 256, 0, stream>>>(qb, kbuf, vbuf, neg, rnd, ctxb);
        attn_greduce<<<dim3(4, NHEAD, BATCH), 256, 0, stream>>>(part, ctxb);

        wconv_kernel<<<dim3(DIM/32, DIM/32), 256, 0, stream>>>(Wo + (size_t)l*DIM*DIM, wt, DIM, DIM);
        gemm_kernel<2><<<dim3(ROWS/128, DIM/128), 256, 0, stream>>>(ctxb, wt, bo + l*DIM, x, x, ROWS, DIM, DIM);

        ln_kernel<1><<<ROWS, 256, 0, stream>>>(x, ln2g + l * DIM, ln2b + l * DIM, xn_b);

        wconv_kernel<<<dim3(DIM/32, FFDIM/32), 256, 0, stream>>>(W1 + (size_t)l*DIM*FFDIM, wt, DIM, FFDIM);
        gemm_kernel<1><<<dim3(ROWS/128, FFDIM/128), 256, 0, stream>>>(xn_b, wt, b1 + l*FFDIM, nullptr, ffb, ROWS, FFDIM, DIM);
        wconv_kernel<<<dim3(FFDIM/32, DIM/32), 256, 0, stream>>>(W2 + (size_t)l*FFDIM*DIM, wt, FFDIM, DIM);
        gemm_kernel<2><<<dim3(ROWS/128, DIM/128), 256, 0, stream>>>(ffb, wt, b2 + l*DIM, x, x, ROWS, DIM, FFDIM);
    }

    ln_kernel<0><<<ROWS, 256, 0, stream>>>(x, lnfg, lnfb, xn_f);
    colmean_kernel<<<dim3(32, BATCH), 256, 0, stream>>>(xn_f, feats);
    head_kernel<<<BATCH, 256, 0, stream>>>(feats, projW, projb, out);
}

// Round 3
// 1971.938 us; speedup vs baseline: 3.0429x; 3.0429x over previous
//
#include <hip/hip_runtime.h>
#include <hip/hip_bf16.h>
#include <cstdint>
#include <cstddef>

#define BATCH 2
#define SEQ   4096
#define DIM   1024
#define NHEAD 16
#define HDIM  64
#define NBLK  64
#define NMID  62
#define NRAND 3
#define NLAYER 4
#define FFDIM 4096
#define ROWS  (BATCH*SEQ)   // 8192
#define KSPL  8             // key splits for global attention

using f32x4 = __attribute__((ext_vector_type(4))) float;
using s16x8 = __attribute__((ext_vector_type(8))) short;
using s16x4 = __attribute__((ext_vector_type(4))) short;

__device__ inline float bf2f(short s) {
    unsigned u = ((unsigned)(unsigned short)s) << 16;
    union { unsigned u; float f; } cv; cv.u = u; return cv.f;
}
__device__ inline short f2bf(float f) {
    union { float f; unsigned u; } cv; cv.f = f;
    unsigned u = cv.u;
    unsigned r = (u + 0x7fffu + ((u >> 16) & 1u)) >> 16;  // RNE
    return (short)r;
}
__device__ inline float gelu_f(float x) {
    float u = 0.7978845608028654f * (x + 0.044715f * x * x * x);
    return 0.5f * x * (1.f + tanhf(u));
}

// ---------------------------------------------------------------- embedding
__global__ __launch_bounds__(256) void embed_kernel(
    const int* __restrict__ ids, const float* __restrict__ emb, float* __restrict__ x)
{
    int row = blockIdx.x;
    int id  = ids[row];
    ((float4*)x)[(size_t)row * 256 + threadIdx.x] =
        ((const float4*)emb)[(size_t)id * 256 + threadIdx.x];
}

// ---------------------------------------------------------------- neg mask
__global__ __launch_bounds__(256) void neg_kernel(
    const int* __restrict__ mask, float* __restrict__ neg)
{
    int i = blockIdx.x * 256 + threadIdx.x;
    if (i < ROWS) neg[i] = (1.f - (float)mask[i]) * -1e9f;
}

// ---------------------------------------------------------------- layernorm (row=1024)
template<int OUTBF>
__global__ __launch_bounds__(256) void ln_kernel(
    const float* __restrict__ x, const float* __restrict__ g,
    const float* __restrict__ bia, void* __restrict__ out)
{
    __shared__ float s1[4], s2[4];
    int row = blockIdx.x, t = threadIdx.x;
    const float* xr = x + (size_t)row * DIM;
    float4 v = ((const float4*)xr)[t];
    float s = v.x + v.y + v.z + v.w;
    #pragma unroll
    for (int o = 32; o > 0; o >>= 1) s += __shfl_xor(s, o, 64);
    if ((t & 63) == 0) s1[t >> 6] = s;
    __syncthreads();
    float mu = (s1[0] + s1[1] + s1[2] + s1[3]) * (1.f / DIM);
    float dx = v.x - mu, dy = v.y - mu, dz = v.z - mu, dw = v.w - mu;
    float q = dx*dx + dy*dy + dz*dz + dw*dw;
    #pragma unroll
    for (int o = 32; o > 0; o >>= 1) q += __shfl_xor(q, o, 64);
    if ((t & 63) == 0) s2[t >> 6] = q;
    __syncthreads();
    float var = (s2[0] + s2[1] + s2[2] + s2[3]) * (1.f / DIM);
    float rs  = rsqrtf(var + 1e-5f);
    float4 gg = ((const float4*)g)[t];
    float4 bb = ((const float4*)bia)[t];
    float o0 = dx * rs * gg.x + bb.x;
    float o1 = dy * rs * gg.y + bb.y;
    float o2 = dz * rs * gg.z + bb.z;
    float o3 = dw * rs * gg.w + bb.w;
    if (OUTBF) {
        s16x4 ov = { f2bf(o0), f2bf(o1), f2bf(o2), f2bf(o3) };
        ((s16x4*)out)[(size_t)row * (DIM/4) + t] = ov;
    } else {
        float4 ov = { o0, o1, o2, o3 };
        ((float4*)out)[(size_t)row * (DIM/4) + t] = ov;
    }
}

// ---------------------------------------------------------------- weight transpose + bf16
__global__ __launch_bounds__(256) void wconv_kernel(
    const float* __restrict__ W, short* __restrict__ Wt, int K, int N)
{
    __shared__ float tile[32][33];
    int k0 = blockIdx.x * 32, n0 = blockIdx.y * 32;
    int t = threadIdx.x;
    int r = t >> 3, c = (t & 7) * 4;
    float4 v = *(const float4*)(W + (size_t)(k0 + r) * N + n0 + c);
    tile[r][c+0] = v.x; tile[r][c+1] = v.y; tile[r][c+2] = v.z; tile[r][c+3] = v.w;
    __syncthreads();
    s16x4 ov;
    #pragma unroll
    for (int jj = 0; jj < 4; ++jj) ov[jj] = f2bf(tile[c + jj][r]);
    *(s16x4*)(Wt + (size_t)(n0 + r) * K + k0 + c) = ov;
}

// ---------------------------------------------------------------- V transpose (per head)
// vbuf[token][h*64+d] -> vT[(b*H+h)*64+d][token]
__global__ __launch_bounds__(256) void vtrans_kernel(
    const short* __restrict__ vbuf, short* __restrict__ vT)
{
    __shared__ short tile[64][66];
    const int sb = blockIdx.x, h = blockIdx.y, b = blockIdx.z;
    const int t = threadIdx.x;
    {
        int row = t >> 2, c0 = (t & 3) * 16;
        const short* src = vbuf + (size_t)(b * SEQ + sb * 64 + row) * DIM + h * HDIM + c0;
        s16x8 a0 = ((const s16x8*)src)[0];
        s16x8 a1 = ((const s16x8*)src)[1];
        #pragma unroll
        for (int i = 0; i < 8; ++i) { tile[row][c0 + i] = a0[i]; tile[row][c0 + 8 + i] = a1[i]; }
    }
    __syncthreads();
    {
        int d = t >> 2, k0 = (t & 3) * 16;
        s16x8 o0, o1;
        #pragma unroll
        for (int i = 0; i < 8; ++i) { o0[i] = tile[k0 + i][d]; o1[i] = tile[k0 + 8 + i][d]; }
        short* dst = vT + (size_t)((b * NHEAD + h) * HDIM + d) * SEQ + sb * 64 + k0;
        ((s16x8*)dst)[0] = o0;
        ((s16x8*)dst)[1] = o1;
    }
}

// ---------------------------------------------------------------- GEMM (bf16 MFMA)
template<int EPI>
__global__ __launch_bounds__(256) void gemm_kernel(
    const short* __restrict__ A, const short* __restrict__ Bt,
    const float* __restrict__ bias, const float* __restrict__ resid,
    void* __restrict__ Cout, int M, int N, int K)
{
    __shared__ short As[128 * 64];
    __shared__ short Bs[128 * 64];
    const int t = threadIdx.x;
    const int m0 = blockIdx.x * 128, n0 = blockIdx.y * 128;
    const int lane = t & 63, wave = t >> 6;
    const int wr = (wave >> 1) * 64, wc = (wave & 1) * 64;
    const int srow = t >> 3;
    const int scolb = (t & 7) * 16;

    f32x4 acc[4][4];
    #pragma unroll
    for (int m = 0; m < 4; ++m)
        #pragma unroll
        for (int n = 0; n < 4; ++n)
            acc[m][n] = f32x4{0.f, 0.f, 0.f, 0.f};

    const short* Arow = A  + (size_t)(m0 + srow) * K + (scolb >> 1);
    const short* Brow = Bt + (size_t)(n0 + srow) * K + (scolb >> 1);

    for (int kt = 0; kt < K; kt += 64) {
        s16x8 ra[4], rb[4];
        #pragma unroll
        for (int p = 0; p < 4; ++p) {
            ra[p] = *(const s16x8*)(Arow + (size_t)(p * 32) * K + kt);
            rb[p] = *(const s16x8*)(Brow + (size_t)(p * 32) * K + kt);
        }
        __syncthreads();
        #pragma unroll
        for (int p = 0; p < 4; ++p) {
            int row = p * 32 + srow;
            int boff = row * 128 + (scolb ^ ((row & 7) << 4));
            *(s16x8*)((char*)As + boff) = ra[p];
            *(s16x8*)((char*)Bs + boff) = rb[p];
        }
        __syncthreads();
        #pragma unroll
        for (int kk = 0; kk < 2; ++kk) {
            s16x8 af[4], bfr[4];
            #pragma unroll
            for (int i = 0; i < 4; ++i) {
                int cb = kk * 64 + ((lane >> 4) << 4);
                int r  = wr + i * 16 + (lane & 15);
                af[i]  = *(const s16x8*)((const char*)As + r * 128 + (cb ^ ((r & 7) << 4)));
                int r2 = wc + i * 16 + (lane & 15);
                bfr[i] = *(const s16x8*)((const char*)Bs + r2 * 128 + (cb ^ ((r2 & 7) << 4)));
            }
            #pragma unroll
            for (int m = 0; m < 4; ++m)
                #pragma unroll
                for (int n = 0; n < 4; ++n)
                    acc[m][n] = __builtin_amdgcn_mfma_f32_16x16x32_bf16(
                        af[m], bfr[n], acc[m][n], 0, 0, 0);
        }
    }

    const int rbase = m0 + wr + ((lane >> 4) << 2);
    const int cbase = n0 + wc + (lane & 15);
    #pragma unroll
    for (int m = 0; m < 4; ++m) {
        #pragma unroll
        for (int n = 0; n < 4; ++n) {
            #pragma unroll
            for (int j = 0; j < 4; ++j) {
                int row = rbase + m * 16 + j;
                int col = cbase + n * 16;
                float val = acc[m][n][j] + bias[col];
                size_t idx = (size_t)row * N + col;
                if (EPI == 1) val = gelu_f(val);
                if (EPI == 2) ((float*)Cout)[idx] = val + resid[idx];
                else          ((short*)Cout)[idx] = f2bf(val);
            }
        }
    }
}

// ================================================================ MFMA attention
// One block = (b, h, 64 q-rows); 4 waves, wave owns 16 q-rows.
// S^T = K*Q^T via mfma (lane holds 16 k-scores for one q-col), in-register
// online softmax (shfl_xor 16/32 row-reduce), PV as O^T = V^T * P^T with the
// P^T B-fragment built by an 8-shfl cross-lane exchange.
// LDS tiles XOR-swizzled: byte = row*128 + col*2 ^ ((row&7)<<4).

// Process one 64-key tile: stage K/V^T/mask, QK^T, softmax-update, PV.
__device__ inline void attn_tile_mfma(
    const short* __restrict__ kglob,   // &k[(b*SEQ+kbn*64)*DIM + h*64]
    const short* __restrict__ vtglob,  // &vT[(b*H+h)*64*SEQ + kbn*64]
    const float* __restrict__ negp,    // &neg[b*SEQ + kbn*64]
    short* Ks, short* Vs, float* kmask,
    const s16x8* qfrag, f32x4* o, float& mr, float& lsum)
{
    const int t = threadIdx.x;
    const int lane = t & 63;
    const int q15 = lane & 15, g = lane >> 4;
    const int sw = (lane & 7) << 4;

    {   // stage K (row-major [k][d]) and V^T (row-major [d][k]), both swizzled
        int row = t >> 2, c0 = (t & 3) * 16;   // 64 rows x 4 chunks of 16 elems
        int rsw = (row & 7) << 4;
        const short* ksrc = kglob + (size_t)row * DIM + c0;
        s16x8 a0 = ((const s16x8*)ksrc)[0];
        s16x8 a1 = ((const s16x8*)ksrc)[1];
        char* kdst = (char*)Ks + row * 128;
        *(s16x8*)(kdst + ((c0 * 2)      ^ rsw)) = a0;
        *(s16x8*)(kdst + ((c0 * 2 + 16) ^ rsw)) = a1;
        const short* vsrc = vtglob + (size_t)row * SEQ + c0;
        s16x8 b0 = ((const s16x8*)vsrc)[0];
        s16x8 b1 = ((const s16x8*)vsrc)[1];
        char* vdst = (char*)Vs + row * 128;
        *(s16x8*)(vdst + ((c0 * 2)      ^ rsw)) = b0;
        *(s16x8*)(vdst + ((c0 * 2 + 16) ^ rsw)) = b1;
        if (t < 16) ((float4*)kmask)[t] = ((const float4*)negp)[t];
    }
    __syncthreads();

    // QK: S^T[k][q], k = 16f + 4g + j, q = wave*16 + q15
    f32x4 s[4];
    #pragma unroll
    for (int f = 0; f < 4; ++f) s[f] = f32x4{0.f, 0.f, 0.f, 0.f};
    #pragma unroll
    for (int ch = 0; ch < 2; ++ch) {
        #pragma unroll
        for (int f = 0; f < 4; ++f) {
            s16x8 kf = *(const s16x8*)((const char*)Ks + (16 * f + q15) * 128 + ((ch * 64 + g * 16) ^ sw));
            s[f] = __builtin_amdgcn_mfma_f32_16x16x32_bf16(kf, qfrag[ch], s[f], 0, 0, 0);
        }
    }

    // softmax (scale + mask + online max/sum across lane's 16 + xor 16/32)
    float p[4][4];
    float mt = -1e30f;
    #pragma unroll
    for (int f = 0; f < 4; ++f) {
        float4 km = ((const float4*)kmask)[f * 4 + g];
        #pragma unroll
        for (int j = 0; j < 4; ++j) {
            float val = s[f][j] * 0.125f + ((const float*)&km)[j];
            p[f][j] = val;
            mt = fmaxf(mt, val);
        }
    }
    mt = fmaxf(mt, __shfl_xor(mt, 16, 64));
    mt = fmaxf(mt, __shfl_xor(mt, 32, 64));
    float mn = fmaxf(mr, mt);
    float psum = 0.f;
    #pragma unroll
    for (int f = 0; f < 4; ++f)
        #pragma unroll
        for (int j = 0; j < 4; ++j) {
            float e = __expf(p[f][j] - mn);
            p[f][j] = e;
            psum += e;
        }
    psum += __shfl_xor(psum, 16, 64);
    psum += __shfl_xor(psum, 32, 64);
    float fc = __expf(mr - mn);
    mr = mn;
    lsum = lsum * fc + psum;
    #pragma unroll
    for (int dt = 0; dt < 4; ++dt)
        #pragma unroll
        for (int j = 0; j < 4; ++j) o[dt][j] *= fc;

    // pack P -> bf16 pairs: pk[f][pp] holds k = 16f+4g+2pp (lo), +1 (hi)
    unsigned pk[4][2];
    #pragma unroll
    for (int f = 0; f < 4; ++f)
        #pragma unroll
        for (int pp = 0; pp < 2; ++pp)
            pk[f][pp] = ((unsigned)(unsigned short)f2bf(p[f][2 * pp + 1]) << 16)
                      |  (unsigned)(unsigned short)f2bf(p[f][2 * pp]);

    // PV: O^T[d][q] += V^T[d][k] * P^T[k][q]
    const int bsel = (lane >> 4) & 1, asel = (lane >> 5) & 1;
    #pragma unroll
    for (int c = 0; c < 2; ++c) {
        union { s16x8 v; int u[4]; } pb;
        #pragma unroll
        for (int w = 0; w < 4; ++w) {
            int src = q15 + 16 * (2 * bsel + (w >> 1));
            int lo = __shfl((int)pk[2 * c][w & 1], src, 64);
            int hi = __shfl((int)pk[2 * c + 1][w & 1], src, 64);
            pb.u[w] = asel ? hi : lo;
        }
        #pragma unroll
        for (int dt = 0; dt < 4; ++dt) {
            s16x8 vf = *(const s16x8*)((const char*)Vs + (16 * dt + q15) * 128 + ((c * 64 + g * 16) ^ sw));
            o[dt] = __builtin_amdgcn_mfma_f32_16x16x32_bf16(vf, pb.v, o[dt], 0, 0, 0);
        }
    }
    __syncthreads();   // tile fully consumed before next staging
}

__device__ inline void stage_q64_swz(const short* __restrict__ qglob, short* Qs)
{
    int t = threadIdx.x;
    int row = t >> 2, c0 = (t & 3) * 16;
    int rsw = (row & 7) << 4;
    const short* src = qglob + (size_t)row * DIM + c0;
    s16x8 a0 = ((const s16x8*)src)[0];
    s16x8 a1 = ((const s16x8*)src)[1];
    char* dst = (char*)Qs + row * 128;
    *(s16x8*)(dst + ((c0 * 2)      ^ rsw)) = a0;
    *(s16x8*)(dst + ((c0 * 2 + 16) ^ rsw)) = a1;
}

// ---------------------------------------------------------------- middle blocks
__global__ __launch_bounds__(256) void attn_middle_mfma(
    const short* __restrict__ q, const short* __restrict__ k, const short* __restrict__ vT,
    const float* __restrict__ neg, const int* __restrict__ rand_attn, short* __restrict__ ctx)
{
    __shared__ short Qs[64 * 64];
    __shared__ short Ks[64 * 64];
    __shared__ short Vs[64 * 64];
    __shared__ float kmask[64];

    const int j = blockIdx.x, h = blockIdx.y, b = blockIdx.z;
    const int n = j + 1;
    const int t = threadIdx.x;
    const int lane = t & 63, wave = t >> 6;
    const int q15 = lane & 15, g = lane >> 4;
    const int sw = (lane & 7) << 4;

    stage_q64_swz(q + (size_t)(b * SEQ + n * 64) * DIM + h * HDIM, Qs);
    __syncthreads();

    // hoist Q fragments (q = wave*16 + q15)
    s16x8 qfrag[2];
    {
        int qrow = wave * 16 + q15;
        #pragma unroll
        for (int ch = 0; ch < 2; ++ch)
            qfrag[ch] = *(const s16x8*)((const char*)Qs + qrow * 128 + ((ch * 64 + g * 16) ^ sw));
    }

    int kbl[8];
    kbl[0] = n - 1; kbl[1] = n; kbl[2] = n + 1; kbl[3] = 0; kbl[4] = NBLK - 1;
    {
        const int* ra = rand_attn + ((size_t)h * NMID + j) * NRAND;
        kbl[5] = ra[0]; kbl[6] = ra[1]; kbl[7] = ra[2];
    }

    f32x4 o[4];
    #pragma unroll
    for (int dt = 0; dt < 4; ++dt) o[dt] = f32x4{0.f, 0.f, 0.f, 0.f};
    float mr = -1e30f, lsum = 0.f;

    const short* kbase  = k  + (size_t)b * SEQ * DIM + h * HDIM;
    const short* vtbase = vT + (size_t)(b * NHEAD + h) * HDIM * SEQ;
    const float* negb   = neg + (size_t)b * SEQ;

    #pragma unroll 1
    for (int ib = 0; ib < 8; ++ib) {
        int kbn = kbl[ib];
        attn_tile_mfma(kbase + (size_t)kbn * 64 * DIM, vtbase + kbn * 64,
                       negb + kbn * 64, Ks, Vs, kmask, qfrag, o, mr, lsum);
    }

    float inv = 1.f / lsum;
    short* obase = ctx + (size_t)(b * SEQ + n * 64 + wave * 16 + q15) * DIM + h * HDIM;
    #pragma unroll
    for (int dt = 0; dt < 4; ++dt) {
        s16x4 ov;
        #pragma unroll
        for (int jj = 0; jj < 4; ++jj) ov[jj] = f2bf(o[dt][jj] * inv);
        *(s16x4*)(obase + dt * 16 + g * 4) = ov;
    }
}

// ---------------------------------------------------------------- global blocks, split-K
// grid (2*KSPL, H, B): qb = bx>>3 (block 0 or 63), ks = bx&7 (8 key-blocks)
// partial region per (b,h,qb,ks): O[64][64] + m[64] + l[64] = 4224 floats
__global__ __launch_bounds__(256) void attn_global_mfma(
    const short* __restrict__ q, const short* __restrict__ k, const short* __restrict__ vT,
    const float* __restrict__ neg, float* __restrict__ part)
{
    __shared__ short Qs[64 * 64];
    __shared__ short Ks[64 * 64];
    __shared__ short Vs[64 * 64];
    __shared__ float kmask[64];

    const int qb = blockIdx.x >> 3, ks = blockIdx.x & 7;
    const int h = blockIdx.y, b = blockIdx.z;
    const int tok0 = qb ? (SEQ - 64) : 0;
    const int t = threadIdx.x;
    const int lane = t & 63, wave = t >> 6;
    const int q15 = lane & 15, g = lane >> 4;
    const int sw = (lane & 7) << 4;

    stage_q64_swz(q + (size_t)(b * SEQ + tok0) * DIM + h * HDIM, Qs);
    __syncthreads();

    s16x8 qfrag[2];
    {
        int qrow = wave * 16 + q15;
        #pragma unroll
        for (int ch = 0; ch < 2; ++ch)
            qfrag[ch] = *(const s16x8*)((const char*)Qs + qrow * 128 + ((ch * 64 + g * 16) ^ sw));
    }

    f32x4 o[4];
    #pragma unroll
    for (int dt = 0; dt < 4; ++dt) o[dt] = f32x4{0.f, 0.f, 0.f, 0.f};
    float mr = -1e30f, lsum = 0.f;

    const short* kbase  = k  + (size_t)b * SEQ * DIM + h * HDIM;
    const short* vtbase = vT + (size_t)(b * NHEAD + h) * HDIM * SEQ;
    const float* negb   = neg + (size_t)b * SEQ;

    #pragma unroll 1
    for (int ib = 0; ib < 8; ++ib) {
        int kbn = ks * 8 + ib;
        attn_tile_mfma(kbase + (size_t)kbn * 64 * DIM, vtbase + kbn * 64,
                       negb + kbn * 64, Ks, Vs, kmask, qfrag, o, mr, lsum);
    }

    float* pbase = part + ((size_t)(((b * NHEAD + h) * 2 + qb) * KSPL + ks)) * 4224;
    int qrow = wave * 16 + q15;
    #pragma unroll
    for (int dt = 0; dt < 4; ++dt)
        *(f32x4*)(pbase + qrow * 64 + dt * 16 + g * 4) = o[dt];
    if (g == 0) { pbase[4096 + qrow] = mr; pbase[4160 + qrow] = lsum; }
}

// ---------------------------------------------------------------- merge global partials
__global__ __launch_bounds__(256) void attn_greduce(
    const float* __restrict__ part, short* __restrict__ ctx)
{
    const int qb = blockIdx.x, h = blockIdx.y, b = blockIdx.z;
    const int tok0 = qb ? (SEQ - 64) : 0;
    const int t = threadIdx.x;
    const int qq = t >> 2, d0 = (t & 3) * 16;
    const float* base = part + ((size_t)(((b * NHEAD + h) * 2 + qb) * KSPL)) * 4224;

    float m = -1e30f;
    #pragma unroll 1
    for (int s = 0; s < KSPL; ++s)
        m = fmaxf(m, base[(size_t)s * 4224 + 4096 + qq]);
    float L = 0.f;
    float acc[16];
    #pragma unroll
    for (int i = 0; i < 16; ++i) acc[i] = 0.f;
    #pragma unroll 1
    for (int s = 0; s < KSPL; ++s) {
        const float* bp = base + (size_t)s * 4224;
        float w = __expf(bp[4096 + qq] - m);
        L += w * bp[4160 + qq];
        const float4* row = (const float4*)(bp + qq * 64 + d0);
        #pragma unroll
        for (int v4 = 0; v4 < 4; ++v4) {
            float4 val = row[v4];
            acc[v4 * 4 + 0] = fmaf(w, val.x, acc[v4 * 4 + 0]);
            acc[v4 * 4 + 1] = fmaf(w, val.y, acc[v4 * 4 + 1]);
            acc[v4 * 4 + 2] = fmaf(w, val.z, acc[v4 * 4 + 2]);
            acc[v4 * 4 + 3] = fmaf(w, val.w, acc[v4 * 4 + 3]);
        }
    }
    float inv = 1.f / L;
    short* dst = ctx + (size_t)(b * SEQ + tok0 + qq) * DIM + h * HDIM + d0;
    s16x8 o0, o1;
    #pragma unroll
    for (int i = 0; i < 8; ++i) { o0[i] = f2bf(acc[i] * inv); o1[i] = f2bf(acc[8 + i] * inv); }
    ((s16x8*)dst)[0] = o0;
    ((s16x8*)dst)[1] = o1;
}

// ---------------------------------------------------------------- mean over S per (b,d)
__global__ __launch_bounds__(256) void colmean_kernel(
    const float* __restrict__ xln, float* __restrict__ feats)
{
    __shared__ float red[8][33];
    int c = blockIdx.x, b = blockIdx.y;
    int dd = threadIdx.x & 31, rg = threadIdx.x >> 5;
    const float* base = xln + (size_t)b * SEQ * DIM + c * 32 + dd;
    float s = 0.f;
    for (int rr = rg; rr < SEQ; rr += 8) s += base[(size_t)rr * DIM];
    red[rg][dd] = s;
    __syncthreads();
    if (rg == 0) {
        float tot = s;
        #pragma unroll
        for (int i = 1; i < 8; ++i) tot += red[i][dd];
        feats[b * DIM + c * 32 + dd] = tot * (1.f / SEQ);
    }
}

// ---------------------------------------------------------------- normalize + project
__global__ __launch_bounds__(256) void head_kernel(
    const float* __restrict__ feats, const float* __restrict__ projW,
    const float* __restrict__ projb, float* __restrict__ out)
{
    __shared__ float f[DIM];
    __shared__ float slots[4];
    int b = blockIdx.x, t = threadIdx.x;
    float ss = 0.f;
    for (int i = t; i < DIM; i += 256) {
        float vv = feats[b * DIM + i];
        f[i] = vv;
        ss += vv * vv;
    }
    #pragma unroll
    for (int o = 32; o > 0; o >>= 1) ss += __shfl_xor(ss, o, 64);
    if ((t & 63) == 0) slots[t >> 6] = ss;
    __syncthreads();
    float nrm = sqrtf(slots[0] + slots[1] + slots[2] + slots[3]);
    float inv = 1.f / fmaxf(nrm, 1e-12f);
    for (int o = t; o < 512; o += 256) {
        float acc = 0.f;
        for (int d = 0; d < DIM; ++d)
            acc = fmaf(f[d], projW[(size_t)d * 512 + o], acc);
        out[b * 512 + o] = acc * inv + projb[o];
    }
}

// ---------------------------------------------------------------- launch
extern "C" void kernel_launch(void* const* d_in, const int* in_sizes, int n_in,
                              void* d_out, int out_size, void* d_ws, size_t ws_size,
                              hipStream_t stream)
{
    (void)in_sizes; (void)n_in; (void)out_size; (void)ws_size;
    const int*   ids   = (const int*)d_in[0];
    const int*   amask = (const int*)d_in[1];
    const int*   rnd   = (const int*)d_in[2];
    const float* emb   = (const float*)d_in[3];
    const float* Wq    = (const float*)d_in[4];
    const float* bq    = (const float*)d_in[5];
    const float* Wk    = (const float*)d_in[6];
    const float* bk    = (const float*)d_in[7];
    const float* Wv    = (const float*)d_in[8];
    const float* bv    = (const float*)d_in[9];
    const float* Wo    = (const float*)d_in[10];
    const float* bo    = (const float*)d_in[11];
    const float* ln1g  = (const float*)d_in[12];
    const float* ln1b  = (const float*)d_in[13];
    const float* W1    = (const float*)d_in[14];
    const float* b1    = (const float*)d_in[15];
    const float* W2    = (const float*)d_in[16];
    const float* b2    = (const float*)d_in[17];
    const float* ln2g  = (const float*)d_in[18];
    const float* ln2b  = (const float*)d_in[19];
    const float* lnfg  = (const float*)d_in[20];
    const float* lnfb  = (const float*)d_in[21];
    const float* projW = (const float*)d_in[22];
    const float* projb = (const float*)d_in[23];
    float* out = (float*)d_out;

    char* ws = (char*)d_ws;
    size_t off = 0;
    float* x    = (float*)(ws + off); off += (size_t)ROWS * DIM * 4;
    float* xn_f = (float*)(ws + off);
    short* xn_b = (short*)(ws + off); off += (size_t)ROWS * DIM * 4;
    short* qb   = (short*)(ws + off); off += (size_t)ROWS * DIM * 2;
    short* kbuf = (short*)(ws + off); off += (size_t)ROWS * DIM * 2;
    short* vbuf = (short*)(ws + off); off += (size_t)ROWS * DIM * 2;
    short* vT   = (short*)(ws + off); off += (size_t)ROWS * DIM * 2;
    short* ctxb = (short*)(ws + off); off += (size_t)ROWS * DIM * 2;
    short* ffb  = (short*)(ws + off); off += (size_t)ROWS * FFDIM * 2;
    short* wt   = (short*)(ws + off); off += (size_t)FFDIM * DIM * 2;
    float* neg  = (float*)(ws + off); off += (size_t)ROWS * 4;
    float* feats= (float*)(ws + off); off += (size_t)BATCH * DIM * 4;
    float* part = (float*)(ws + off); off += (size_t)BATCH * NHEAD * 2 * KSPL * 4224 * 4;

    embed_kernel<<<ROWS, 256, 0, stream>>>(ids, emb, x);
    neg_kernel<<<(ROWS + 255) / 256, 256, 0, stream>>>(amask, neg);

    for (int l = 0; l < NLAYER; ++l) {
        ln_kernel<1><<<ROWS, 256, 0, stream>>>(x, ln1g + l * DIM, ln1b + l * DIM, xn_b);

        wconv_kernel<<<dim3(DIM/32, DIM/32), 256, 0, stream>>>(Wq + (size_t)l*DIM*DIM, wt, DIM, DIM);
        gemm_kernel<0><<<dim3(ROWS/128, DIM/128), 256, 0, stream>>>(xn_b, wt, bq + l*DIM, nullptr, qb,   ROWS, DIM, DIM);
        wconv_kernel<<<dim3(DIM/32, DIM/32), 256, 0, stream>>>(Wk + (size_t)l*DIM*DIM, wt, DIM, DIM);
        gemm_kernel<0><<<dim3(ROWS/128, DIM/128), 256, 0, stream>>>(xn_b, wt, bk + l*DIM, nullptr, kbuf, ROWS, DIM, DIM);
        wconv_kernel<<<dim3(DIM/32, DIM/32), 256, 0, stream>>>(Wv + (size_t)l*DIM*DIM, wt, DIM, DIM);
        gemm_kernel<0><<<dim3(ROWS/128, DIM/128), 256, 0, stream>>>(xn_b, wt, bv + l*DIM, nullptr, vbuf, ROWS, DIM, DIM);

        vtrans_kernel<<<dim3(SEQ/64, NHEAD, BATCH), 256, 0, stream>>>(vbuf, vT);

        attn_global_mfma<<<dim3(2 * KSPL, NHEAD, BATCH), 256, 0, stream>>>(qb, kbuf, vT, neg, part);
        attn_middle_mfma<<<dim3(NMID, NHEAD, BATCH), 256, 0, stream>>>(qb, kbuf, vT, neg, rnd, ctxb);
        attn_greduce<<<dim3(2, NHEAD, BATCH), 256, 0, stream>>>(part, ctxb);

        wconv_kernel<<<dim3(DIM/32, DIM/32), 256, 0, stream>>>(Wo + (size_t)l*DIM*DIM, wt, DIM, DIM);
        gemm_kernel<2><<<dim3(ROWS/128, DIM/128), 256, 0, stream>>>(ctxb, wt, bo + l*DIM, x, x, ROWS, DIM, DIM);

        ln_kernel<1><<<ROWS, 256, 0, stream>>>(x, ln2g + l * DIM, ln2b + l * DIM, xn_b);

        wconv_kernel<<<dim3(DIM/32, FFDIM/32), 256, 0, stream>>>(W1 + (size_t)l*DIM*FFDIM, wt, DIM, FFDIM);
        gemm_kernel<1><<<dim3(ROWS/128, FFDIM/128), 256, 0, stream>>>(xn_b, wt, b1 + l*FFDIM, nullptr, ffb, ROWS, FFDIM, DIM);
        wconv_kernel<<<dim3(FFDIM/32, DIM/32), 256, 0, stream>>>(W2 + (size_t)l*FFDIM*DIM, wt, FFDIM, DIM);
        gemm_kernel<2><<<dim3(ROWS/128, DIM/128), 256, 0, stream>>>(ffb, wt, b2 + l*DIM, x, x, ROWS, DIM, FFDIM);
    }

    ln_kernel<0><<<ROWS, 256, 0, stream>>>(x, lnfg, lnfb, xn_f);
    colmean_kernel<<<dim3(32, BATCH), 256, 0, stream>>>(xn_f, feats);
    head_kernel<<<BATCH, 256, 0, stream>>>(feats, projW, projb, out);
}